// Round 2
// baseline (415.515 us; speedup 1.0000x reference)
//
#include <hip/hip_runtime.h>

typedef __attribute__((ext_vector_type(8))) short short8;
typedef __attribute__((ext_vector_type(4))) float f32x4;

#define LC 768
#define DD 256

__device__ __forceinline__ float bf2f(short s) {
  return __uint_as_float(((unsigned)(unsigned short)s) << 16);
}
__device__ __forceinline__ unsigned short f2bf(float f) {
  unsigned u = __float_as_uint(f);
  unsigned rounding = 0x7fffu + ((u >> 16) & 1u);
  return (unsigned short)((u + rounding) >> 16);
}

// ---------------- prep: fp32 -> bf16 conversions + combined weight/bias ----
__global__ void prep_kernel(const float* __restrict__ feats, const float* __restrict__ Wd,
                            const float* __restrict__ Wl, const float* __restrict__ Wr,
                            const float* __restrict__ Gl, const float* __restrict__ Gr,
                            const float* __restrict__ bl, const float* __restrict__ br,
                            const float* __restrict__ bgl, const float* __restrict__ bgr,
                            unsigned short* __restrict__ featsB, unsigned short* __restrict__ WdB,
                            unsigned short* __restrict__ WcB, float* __restrict__ bc)
{
  int idx = blockIdx.x * 256 + threadIdx.x;
  if (idx < 393216) {
    featsB[idx] = f2bf(feats[idx]);
  } else if (idx < 524288) {
    int j = idx - 393216;
    WdB[j] = f2bf(Wd[j]);
  } else if (idx < 1048576) {
    int j = idx - 524288;          // Wc[1024][512]: o = j>>9, k = j&511
    int o = j >> 9, k = j & 511;
    float v;
    if (k < 256) v = (o < 256) ? Wl[o*256 + k] : Gl[(o-256)*256 + k];
    else { int k2 = k - 256; v = (o < 256) ? Wr[o*256 + k2] : Gr[(o-256)*256 + k2]; }
    WcB[j] = f2bf(v);
  } else if (idx < 1049600) {
    int o = idx - 1048576;
    bc[o] = (o < 256) ? bl[o] + br[o] : bgl[o-256] + bgr[o-256];
  }
}

// ---------------- h = feats @ Wd.T + bd  (768x512 @ 512x256) ---------------
__global__ __launch_bounds__(256) void hgemm_kernel(const unsigned short* __restrict__ A,  // [768][512] bf16
                                                    const unsigned short* __restrict__ W,  // [256][512] bf16
                                                    const float* __restrict__ bd,
                                                    unsigned short* __restrict__ C)        // [768][256] bf16
{
  __shared__ __align__(16) unsigned short As[64][72];
  __shared__ __align__(16) unsigned short Ws[64][72];
  int p0 = blockIdx.x * 64;
  int n0 = blockIdx.y * 64;
  int tid = threadIdx.x;
  int wave = tid >> 6, lane = tid & 63;
  f32x4 acc[4];
  #pragma unroll
  for (int i = 0; i < 4; ++i)
    #pragma unroll
    for (int j = 0; j < 4; ++j) acc[i][j] = 0.f;

  int lr = tid >> 3;
  int c8 = (tid & 7) * 8;
  for (int kt = 0; kt < 8; ++kt) {
    int kb = kt * 64;
    #pragma unroll
    for (int rr = 0; rr < 64; rr += 32) {
      int row = lr + rr;
      *(short8*)(&As[row][c8]) = *(const short8*)(A + (size_t)(p0 + row)*512 + kb + c8);
      *(short8*)(&Ws[row][c8]) = *(const short8*)(W + (size_t)(n0 + row)*512 + kb + c8);
    }
    __syncthreads();
    int q8 = (lane >> 4) * 8;
    #pragma unroll
    for (int kk = 0; kk < 2; ++kk) {
      short8 b = *(const short8*)(&Ws[wave*16 + (lane & 15)][kk*32 + q8]);
      #pragma unroll
      for (int mt = 0; mt < 4; ++mt) {
        short8 a = *(const short8*)(&As[mt*16 + (lane & 15)][kk*32 + q8]);
        acc[mt] = __builtin_amdgcn_mfma_f32_16x16x32_bf16(a, b, acc[mt], 0, 0, 0);
      }
    }
    __syncthreads();
  }
  int o = n0 + wave*16 + (lane & 15);
  float bias = bd[o];
  #pragma unroll
  for (int mt = 0; mt < 4; ++mt)
    #pragma unroll
    for (int r = 0; r < 4; ++r) {
      int row = p0 + mt*16 + (lane >> 4)*4 + r;
      C[row*256 + o] = f2bf(acc[mt][r] + bias);
    }
}

// ---------------- one span iteration: GEMM + fused gate epilogue -----------
// A[p][k] = k<256 ? ht[p][k] : ht[p+1][k-256];  C = A @ Wc.T (1024 outs)
// block: 64 rows x (16 cols in each of 4 segments). wave w handles segment w.
__global__ __launch_bounds__(256) void iter_kernel(const unsigned short* __restrict__ htp, // [768][256]
                                                   const unsigned short* __restrict__ Wc,  // [1024][512]
                                                   const float* __restrict__ bc,           // [1024]
                                                   unsigned short* __restrict__ htn,       // [768][256]
                                                   int Mvalid)
{
  __shared__ __align__(16) unsigned short As[64][72];
  __shared__ __align__(16) unsigned short Ws[64][72];
  __shared__ float Cs[64][64];
  int p0 = blockIdx.x * 64;
  int n0 = blockIdx.y * 16;
  int tid = threadIdx.x;
  int wave = tid >> 6, lane = tid & 63;
  f32x4 acc[4];
  #pragma unroll
  for (int i = 0; i < 4; ++i)
    #pragma unroll
    for (int j = 0; j < 4; ++j) acc[i][j] = 0.f;

  int lr = tid >> 3;
  int c8 = (tid & 7) * 8;
  for (int kt = 0; kt < 8; ++kt) {
    int kb = kt * 64;
    int shift = kb >> 8;          // 0 for k<256 (l), 1 for k>=256 (r)
    int kcol = kb & 255;
    #pragma unroll
    for (int rr = 0; rr < 64; rr += 32) {
      int row = lr + rr;
      int grow = p0 + row + shift; if (grow > 767) grow = 767;
      *(short8*)(&As[row][c8]) = *(const short8*)(htp + (size_t)grow*256 + kcol + c8);
      int o = (row >> 4)*256 + n0 + (row & 15);
      *(short8*)(&Ws[row][c8]) = *(const short8*)(Wc + (size_t)o*512 + kb + c8);
    }
    __syncthreads();
    int q8 = (lane >> 4) * 8;
    #pragma unroll
    for (int kk = 0; kk < 2; ++kk) {
      short8 b = *(const short8*)(&Ws[wave*16 + (lane & 15)][kk*32 + q8]);
      #pragma unroll
      for (int mt = 0; mt < 4; ++mt) {
        short8 a = *(const short8*)(&As[mt*16 + (lane & 15)][kk*32 + q8]);
        acc[mt] = __builtin_amdgcn_mfma_f32_16x16x32_bf16(a, b, acc[mt], 0, 0, 0);
      }
    }
    __syncthreads();
  }
  // stash C tile to LDS so one thread can see z,g0,g1,g2 of one (p,d)
  #pragma unroll
  for (int mt = 0; mt < 4; ++mt)
    #pragma unroll
    for (int r = 0; r < 4; ++r)
      Cs[mt*16 + (lane >> 4)*4 + r][wave*16 + (lane & 15)] = acc[mt][r];
  __syncthreads();

  int dl = tid & 15;
  int d = n0 + dl;
  float bz = bc[d], b0 = bc[256 + d], b1 = bc[512 + d], b2v = bc[768 + d];
  for (int pr = tid >> 4; pr < 64; pr += 16) {
    int p = p0 + pr;
    if (p >= Mvalid) continue;
    float z  = Cs[pr][dl]      + bz;
    float g0 = Cs[pr][16 + dl] + b0;
    float g1 = Cs[pr][32 + dl] + b1;
    float g2 = Cs[pr][48 + dl] + b2v;
    float l = bf2f((short)htp[p*256 + d]);
    float r = bf2f((short)htp[(p+1)*256 + d]);
    float hh = 4.f / (1.f + __expf(-z)) - 2.f;
    float mg = fmaxf(g0, fmaxf(g1, g2));
    float e0 = __expf(g0 - mg), e1 = __expf(g1 - mg), e2 = __expf(g2 - mg);
    float inv = 1.f / (e0 + e1 + e2);
    htn[p*256 + d] = f2bf((e0*hh + e1*l + e2*r) * inv);
  }
}

// ---------------- band: B[i][t][k] = Wt[t]·scores(span p=i-8+k, end=i-1)+bt -
__global__ __launch_bounds__(128) void band_kernel(const unsigned short* __restrict__ htall, // [8][768][256]
                                                   const float* __restrict__ Wt,
                                                   const float* __restrict__ bt,
                                                   float* __restrict__ Bband)                // [769][96]
{
  __shared__ __align__(16) unsigned short rows[8][264];
  int i = blockIdx.x + 1;     // 1..768
  int tid = threadIdx.x;
  for (int q = tid; q < 256; q += 128) {
    int k = q >> 5, cc = (q & 31) * 8;
    int p = i - 8 + k, sl = 7 - k;
    short8 v;
    if (p >= 0) {
      v = *(const short8*)(htall + ((size_t)sl*768 + p)*256 + cc);
    } else {
      for (int j = 0; j < 8; ++j) v[j] = 0;
    }
    *(short8*)(&rows[k][cc]) = v;
  }
  __syncthreads();
  if (tid < 96) {
    int t = tid >> 3, k = tid & 7;
    int p = i - 8 + k;
    float res = -1e30f;
    if (p >= 0) {
      float acc = 0.f;
      for (int dch = 0; dch < 256; dch += 8) {
        float4 wa = *(const float4*)(Wt + t*256 + dch);
        float4 wb = *(const float4*)(Wt + t*256 + dch + 4);
        short8 hv = *(const short8*)(&rows[k][dch]);
        acc += wa.x*bf2f(hv[0]) + wa.y*bf2f(hv[1]) + wa.z*bf2f(hv[2]) + wa.w*bf2f(hv[3])
             + wb.x*bf2f(hv[4]) + wb.y*bf2f(hv[5]) + wb.z*bf2f(hv[6]) + wb.w*bf2f(hv[7]);
      }
      res = acc + bt[t];
    }
    Bband[(size_t)i*96 + tid] = res;   // tid = t*8 + k
  }
}

// ---------------- forward recurrence + gold, single wave -------------------
__global__ __launch_bounds__(64) void fwd_kernel(const float* __restrict__ Bband,
                                                 const float* __restrict__ trans,
                                                 const float* __restrict__ bt,
                                                 const int* __restrict__ tags,
                                                 float* __restrict__ out)
{
  int lane = threadIdx.x;
  // ---- gold score ----
  float gold = 0.f;
  for (int s = lane; s < 96; s += 64) {
    int a = tags[s*4+0], b = tags[s*4+1], c = tags[s*4+2], d = tags[s*4+3];
    float v = trans[c*12 + d];
    int sl = b - a;
    if (sl >= 0 && sl < 8) v += Bband[(size_t)(b+1)*96 + d*8 + (7 - sl)];
    else v += bt[d];
    gold += v;
  }
  #pragma unroll
  for (int off = 32; off; off >>= 1) gold += __shfl_down(gold, off);

  // ---- forward pass; lane t owns tag t (lanes >=12 shadow tag 11) ----
  int tt = lane < 12 ? lane : 11;
  float tc[12], Ecol[12];
  #pragma unroll
  for (int tp = 0; tp < 12; ++tp) {
    tc[tp] = trans[tp*12 + tt];
    Ecol[tp] = __expf(tc[tp]);
  }
  float mbuf[8];
  {
    float mx = -1e30f;
    #pragma unroll
    for (int tp = 0; tp < 12; ++tp) mx = fmaxf(mx, tc[tp]);
    float s = 0.f;
    #pragma unroll
    for (int tp = 0; tp < 12; ++tp) s += __expf(tc[tp] - mx);
    float mlow = -10000.f + mx + __logf(s);      // contraction of all -10000 alpha rows
    #pragma unroll
    for (int k = 0; k < 7; ++k) mbuf[k] = mlow;
    float mx2 = -1e30f;
    #pragma unroll
    for (int tp = 0; tp < 12; ++tp) { float vv = ((tp==10)?0.f:-10000.f) + tc[tp]; mx2 = fmaxf(mx2, vv); }
    float s2 = 0.f;
    #pragma unroll
    for (int tp = 0; tp < 12; ++tp) { float vv = ((tp==10)?0.f:-10000.f) + tc[tp]; s2 += __expf(vv - mx2); }
    mbuf[7] = mx2 + __logf(s2);                  // contraction of alpha_0 (START)
  }
  const float* bp0 = Bband + 96 + (size_t)tt*8;
  float4 cxa = *(const float4*)(bp0);
  float4 cxb = *(const float4*)(bp0 + 4);
  float last_na = 0.f;
  for (int i = 1; i <= 768; ++i) {
    float4 nxa = cxa, nxb = cxb;
    if (i < 768) {                               // prefetch next row (off critical path)
      const float* np = Bband + (size_t)(i+1)*96 + tt*8;
      nxa = *(const float4*)(np);
      nxb = *(const float4*)(np + 4);
    }
    float v0 = cxa.x + mbuf[0], v1 = cxa.y + mbuf[1], v2 = cxa.z + mbuf[2], v3 = cxa.w + mbuf[3];
    float v4 = cxb.x + mbuf[4], v5 = cxb.y + mbuf[5], v6 = cxb.z + mbuf[6], v7 = cxb.w + mbuf[7];
    float mx = fmaxf(fmaxf(fmaxf(v0,v1), fmaxf(v2,v3)), fmaxf(fmaxf(v4,v5), fmaxf(v6,v7)));
    float s = __expf(v0-mx)+__expf(v1-mx)+__expf(v2-mx)+__expf(v3-mx)
            + __expf(v4-mx)+__expf(v5-mx)+__expf(v6-mx)+__expf(v7-mx);
    float na = mx + __logf(s);
    float c0 = __shfl(na, 0);                    // shared scale (tag spreads are small)
    float pv = __expf(na - c0);
    float accm = 0.f;
    #pragma unroll
    for (int tp = 0; tp < 12; ++tp) accm = fmaf(__shfl(pv, tp), Ecol[tp], accm);
    float mnew = c0 + __logf(accm);              // LSE_tp(na[tp] + trans[tp][t])
    #pragma unroll
    for (int k = 0; k < 7; ++k) mbuf[k] = mbuf[k+1];
    mbuf[7] = mnew;
    last_na = na;
    cxa = nxa; cxb = nxb;
  }
  float contrib = (lane < 11) ? last_na : 0.f;   // sum over tags 0..10 (:STOP_ID)
  #pragma unroll
  for (int off = 32; off; off >>= 1) contrib += __shfl_down(contrib, off);
  if (lane == 0) out[0] = contrib - gold;
}

// ---------------------------------------------------------------------------
extern "C" void kernel_launch(void* const* d_in, const int* in_sizes, int n_in,
                              void* d_out, int out_size, void* d_ws, size_t ws_size,
                              hipStream_t stream)
{
  const float* feats = (const float*)d_in[0];
  const int*   tags  = (const int*)  d_in[1];
  const float* Wd    = (const float*)d_in[2];
  const float* bd    = (const float*)d_in[3];
  const float* Wl    = (const float*)d_in[4];
  const float* bl    = (const float*)d_in[5];
  const float* Wr    = (const float*)d_in[6];
  const float* br    = (const float*)d_in[7];
  const float* Gl    = (const float*)d_in[8];
  const float* bgl   = (const float*)d_in[9];
  const float* Gr    = (const float*)d_in[10];
  const float* bgr   = (const float*)d_in[11];
  const float* Wt    = (const float*)d_in[12];
  const float* bt    = (const float*)d_in[13];
  const float* trans = (const float*)d_in[14];
  float* out = (float*)d_out;

  char* ws = (char*)d_ws;
  unsigned short* featsB = (unsigned short*)(ws + 0);        // 768*512 bf16
  unsigned short* WdB    = (unsigned short*)(ws + 786432);   // 256*512 bf16
  unsigned short* WcB    = (unsigned short*)(ws + 1048576);  // 1024*512 bf16
  float*          bc     = (float*)         (ws + 2097152);  // 1024 f32
  unsigned short* ht     = (unsigned short*)(ws + 2101248);  // 8*768*256 bf16
  float*          Bband  = (float*)         (ws + 5246976);  // 769*96 f32

  prep_kernel<<<4100, 256, 0, stream>>>(feats, Wd, Wl, Wr, Gl, Gr, bl, br, bgl, bgr,
                                        featsB, WdB, WcB, bc);
  hgemm_kernel<<<dim3(12, 4), 256, 0, stream>>>(featsB, WdB, bd, ht);
  for (int sl = 1; sl <= 7; ++sl)
    iter_kernel<<<dim3(12, 16), 256, 0, stream>>>(ht + (size_t)(sl-1)*768*256, WcB, bc,
                                                  ht + (size_t)sl*768*256, 768 - sl);
  band_kernel<<<768, 128, 0, stream>>>(ht, Wt, bt, Bband);
  fwd_kernel<<<1, 64, 0, stream>>>(Bband, trans, bt, tags, out);
}

// Round 3
// 282.385 us; speedup vs baseline: 1.4714x; 1.4714x over previous
//
#include <hip/hip_runtime.h>

typedef __attribute__((ext_vector_type(8))) short short8;
typedef __attribute__((ext_vector_type(4))) float f32x4;

#define LC 768
#define DD 256

__device__ __forceinline__ float bf2f(short s) {
  return __uint_as_float(((unsigned)(unsigned short)s) << 16);
}
__device__ __forceinline__ unsigned short f2bf(float f) {
  unsigned u = __float_as_uint(f);
  unsigned rounding = 0x7fffu + ((u >> 16) & 1u);
  return (unsigned short)((u + rounding) >> 16);
}

// ---------------- prep: fp32 -> bf16 conversions + combined weight/bias ----
__global__ void prep_kernel(const float* __restrict__ feats, const float* __restrict__ Wd,
                            const float* __restrict__ Wl, const float* __restrict__ Wr,
                            const float* __restrict__ Gl, const float* __restrict__ Gr,
                            const float* __restrict__ bl, const float* __restrict__ br,
                            const float* __restrict__ bgl, const float* __restrict__ bgr,
                            unsigned short* __restrict__ featsB, unsigned short* __restrict__ WdB,
                            unsigned short* __restrict__ WcB, float* __restrict__ bc)
{
  int idx = blockIdx.x * 256 + threadIdx.x;
  if (idx < 393216) {
    featsB[idx] = f2bf(feats[idx]);
  } else if (idx < 524288) {
    int j = idx - 393216;
    WdB[j] = f2bf(Wd[j]);
  } else if (idx < 1048576) {
    int j = idx - 524288;          // Wc[1024][512]: o = j>>9, k = j&511
    int o = j >> 9, k = j & 511;
    float v;
    if (k < 256) v = (o < 256) ? Wl[o*256 + k] : Gl[(o-256)*256 + k];
    else { int k2 = k - 256; v = (o < 256) ? Wr[o*256 + k2] : Gr[(o-256)*256 + k2]; }
    WcB[j] = f2bf(v);
  } else if (idx < 1049600) {
    int o = idx - 1048576;
    bc[o] = (o < 256) ? bl[o] + br[o] : bgl[o-256] + bgr[o-256];
  }
}

// ---------------- h = feats @ Wd.T + bd  (768x512 @ 512x256) ---------------
__global__ __launch_bounds__(256) void hgemm_kernel(const unsigned short* __restrict__ A,  // [768][512] bf16
                                                    const unsigned short* __restrict__ W,  // [256][512] bf16
                                                    const float* __restrict__ bd,
                                                    unsigned short* __restrict__ C)        // [768][256] bf16
{
  __shared__ __align__(16) unsigned short As[64][72];
  __shared__ __align__(16) unsigned short Ws[64][72];
  int p0 = blockIdx.x * 64;
  int n0 = blockIdx.y * 64;
  int tid = threadIdx.x;
  int wave = tid >> 6, lane = tid & 63;
  f32x4 acc[4];
  #pragma unroll
  for (int i = 0; i < 4; ++i)
    #pragma unroll
    for (int j = 0; j < 4; ++j) acc[i][j] = 0.f;

  int lr = tid >> 3;
  int c8 = (tid & 7) * 8;
  for (int kt = 0; kt < 8; ++kt) {
    int kb = kt * 64;
    #pragma unroll
    for (int rr = 0; rr < 64; rr += 32) {
      int row = lr + rr;
      *(short8*)(&As[row][c8]) = *(const short8*)(A + (size_t)(p0 + row)*512 + kb + c8);
      *(short8*)(&Ws[row][c8]) = *(const short8*)(W + (size_t)(n0 + row)*512 + kb + c8);
    }
    __syncthreads();
    int q8 = (lane >> 4) * 8;
    #pragma unroll
    for (int kk = 0; kk < 2; ++kk) {
      short8 b = *(const short8*)(&Ws[wave*16 + (lane & 15)][kk*32 + q8]);
      #pragma unroll
      for (int mt = 0; mt < 4; ++mt) {
        short8 a = *(const short8*)(&As[mt*16 + (lane & 15)][kk*32 + q8]);
        acc[mt] = __builtin_amdgcn_mfma_f32_16x16x32_bf16(a, b, acc[mt], 0, 0, 0);
      }
    }
    __syncthreads();
  }
  int o = n0 + wave*16 + (lane & 15);
  float bias = bd[o];
  #pragma unroll
  for (int mt = 0; mt < 4; ++mt)
    #pragma unroll
    for (int r = 0; r < 4; ++r) {
      int row = p0 + mt*16 + (lane >> 4)*4 + r;
      C[row*256 + o] = f2bf(acc[mt][r] + bias);
    }
}

// ---------------- one span iteration: GEMM + fused gate epilogue -----------
__global__ __launch_bounds__(256) void iter_kernel(const unsigned short* __restrict__ htp, // [768][256]
                                                   const unsigned short* __restrict__ Wc,  // [1024][512]
                                                   const float* __restrict__ bc,           // [1024]
                                                   unsigned short* __restrict__ htn,       // [768][256]
                                                   int Mvalid)
{
  __shared__ __align__(16) unsigned short As[64][72];
  __shared__ __align__(16) unsigned short Ws[64][72];
  __shared__ float Cs[64][64];
  int p0 = blockIdx.x * 64;
  int n0 = blockIdx.y * 16;
  int tid = threadIdx.x;
  int wave = tid >> 6, lane = tid & 63;
  f32x4 acc[4];
  #pragma unroll
  for (int i = 0; i < 4; ++i)
    #pragma unroll
    for (int j = 0; j < 4; ++j) acc[i][j] = 0.f;

  int lr = tid >> 3;
  int c8 = (tid & 7) * 8;
  for (int kt = 0; kt < 8; ++kt) {
    int kb = kt * 64;
    int shift = kb >> 8;          // 0 for k<256 (l), 1 for k>=256 (r)
    int kcol = kb & 255;
    #pragma unroll
    for (int rr = 0; rr < 64; rr += 32) {
      int row = lr + rr;
      int grow = p0 + row + shift; if (grow > 767) grow = 767;
      *(short8*)(&As[row][c8]) = *(const short8*)(htp + (size_t)grow*256 + kcol + c8);
      int o = (row >> 4)*256 + n0 + (row & 15);
      *(short8*)(&Ws[row][c8]) = *(const short8*)(Wc + (size_t)o*512 + kb + c8);
    }
    __syncthreads();
    int q8 = (lane >> 4) * 8;
    #pragma unroll
    for (int kk = 0; kk < 2; ++kk) {
      short8 b = *(const short8*)(&Ws[wave*16 + (lane & 15)][kk*32 + q8]);
      #pragma unroll
      for (int mt = 0; mt < 4; ++mt) {
        short8 a = *(const short8*)(&As[mt*16 + (lane & 15)][kk*32 + q8]);
        acc[mt] = __builtin_amdgcn_mfma_f32_16x16x32_bf16(a, b, acc[mt], 0, 0, 0);
      }
    }
    __syncthreads();
  }
  #pragma unroll
  for (int mt = 0; mt < 4; ++mt)
    #pragma unroll
    for (int r = 0; r < 4; ++r)
      Cs[mt*16 + (lane >> 4)*4 + r][wave*16 + (lane & 15)] = acc[mt][r];
  __syncthreads();

  int dl = tid & 15;
  int d = n0 + dl;
  float bz = bc[d], b0 = bc[256 + d], b1 = bc[512 + d], b2v = bc[768 + d];
  for (int pr = tid >> 4; pr < 64; pr += 16) {
    int p = p0 + pr;
    if (p >= Mvalid) continue;
    float z  = Cs[pr][dl]      + bz;
    float g0 = Cs[pr][16 + dl] + b0;
    float g1 = Cs[pr][32 + dl] + b1;
    float g2 = Cs[pr][48 + dl] + b2v;
    float l = bf2f((short)htp[p*256 + d]);
    float r = bf2f((short)htp[(p+1)*256 + d]);
    float hh = 4.f / (1.f + __expf(-z)) - 2.f;
    float mg = fmaxf(g0, fmaxf(g1, g2));
    float e0 = __expf(g0 - mg), e1 = __expf(g1 - mg), e2 = __expf(g2 - mg);
    float inv = 1.f / (e0 + e1 + e2);
    htn[p*256 + d] = f2bf((e0*hh + e1*l + e2*r) * inv);
  }
}

// ---------------- band: log scores AND exp(scores) ------------------------
__global__ __launch_bounds__(128) void band_kernel(const unsigned short* __restrict__ htall, // [8][768][256]
                                                   const float* __restrict__ Wt,
                                                   const float* __restrict__ bt,
                                                   float* __restrict__ Bband,                // [769][96]
                                                   float* __restrict__ Bexp)                 // [771][96]
{
  __shared__ __align__(16) unsigned short rows[8][264];
  int i = blockIdx.x + 1;     // 1..768
  int tid = threadIdx.x;
  for (int q = tid; q < 256; q += 128) {
    int k = q >> 5, cc = (q & 31) * 8;
    int p = i - 8 + k, sl = 7 - k;
    short8 v;
    if (p >= 0) {
      v = *(const short8*)(htall + ((size_t)sl*768 + p)*256 + cc);
    } else {
      for (int j = 0; j < 8; ++j) v[j] = 0;
    }
    *(short8*)(&rows[k][cc]) = v;
  }
  __syncthreads();
  if (tid < 96) {
    int t = tid >> 3, k = tid & 7;
    int p = i - 8 + k;
    float res = -1e30f;
    if (p >= 0) {
      float acc = 0.f;
      for (int dch = 0; dch < 256; dch += 8) {
        float4 wa = *(const float4*)(Wt + t*256 + dch);
        float4 wb = *(const float4*)(Wt + t*256 + dch + 4);
        short8 hv = *(const short8*)(&rows[k][dch]);
        acc += wa.x*bf2f(hv[0]) + wa.y*bf2f(hv[1]) + wa.z*bf2f(hv[2]) + wa.w*bf2f(hv[3])
             + wb.x*bf2f(hv[4]) + wb.y*bf2f(hv[5]) + wb.z*bf2f(hv[6]) + wb.w*bf2f(hv[7]);
      }
      res = acc + bt[t];
    }
    Bband[(size_t)i*96 + tid] = res;            // log domain (gold)
    Bexp[(size_t)i*96 + tid]  = __expf(res);    // prob domain (forward); exp(-1e30)=0
  }
}

// ---------------- forward recurrence + gold, single wave, prob domain ------
__global__ __launch_bounds__(64) void fwd_kernel(const float* __restrict__ Bband,
                                                 const float* __restrict__ Bexp,
                                                 const float* __restrict__ trans,
                                                 const float* __restrict__ bt,
                                                 const int* __restrict__ tags,
                                                 float* __restrict__ out)
{
  int lane = threadIdx.x;
  // ---- gold score (log domain, unchanged) ----
  float gold = 0.f;
  for (int s = lane; s < 96; s += 64) {
    int a = tags[s*4+0], b = tags[s*4+1], c = tags[s*4+2], d = tags[s*4+3];
    float v = trans[c*12 + d];
    int sl = b - a;
    if (sl >= 0 && sl < 8) v += Bband[(size_t)(b+1)*96 + d*8 + (7 - sl)];
    else v += bt[d];
    gold += v;
  }
  #pragma unroll
  for (int off = 32; off; off >>= 1) gold += __shfl_down(gold, off);

  // ---- forward pass in probability domain with running scale C ----
  // lane t owns tag t (lanes >=12 shadow tag 11).
  // window w[k] = exp(m_{i-8+k} - C);  P = exp(na_i - C);  m contraction:
  // w7' = sum_tp P[tp] * exp(trans[tp][t]).
  int tt = lane < 12 ? lane : 11;
  float Etr[12];
  #pragma unroll
  for (int tp = 0; tp < 12; ++tp) Etr[tp] = __expf(trans[tp*12 + tt]);

  float w0=0.f,w1=0.f,w2=0.f,w3=0.f,w4=0.f,w5=0.f,w6=0.f;
  float w7 = Etr[10];          // G(alpha_0): only START has mass exp(0)=1
  float C = 0.f;

  const float* bp = Bexp + (size_t)tt*8;
  float4 xa0 = *(const float4*)(bp + 96);
  float4 xb0 = *(const float4*)(bp + 96 + 4);
  float4 xa1 = *(const float4*)(bp + 192);
  float4 xb1 = *(const float4*)(bp + 192 + 4);
  float P = 1.f;

  for (int j = 0; j < 192; ++j) {
    #pragma unroll
    for (int u = 0; u < 4; ++u) {
      int i = j*4 + u + 1;
      // prefetch row i+2 (distance-2: ~2 iterations covers L2 latency)
      float4 xa2 = *(const float4*)(bp + (size_t)(i+2)*96);
      float4 xb2 = *(const float4*)(bp + (size_t)(i+2)*96 + 4);
      // P = sum_k eX[k]*w[k]; first 7 terms independent of w7
      float partial = xa0.x*w0 + xa0.y*w1 + xa0.z*w2 + xa0.w*w3
                    + xb0.x*w4 + xb0.y*w5 + xb0.z*w6;
      P = fmaf(xb0.w, w7, partial);
      // contraction: em[t] = sum_tp P[tp]*Etr[tp]
      float p0s = __shfl(P, 0);
      float c0 = fmaf(p0s,          Etr[0], fmaf(__shfl(P, 1), Etr[1], __shfl(P, 2)*Etr[2]));
      float c1 = fmaf(__shfl(P, 3), Etr[3], fmaf(__shfl(P, 4), Etr[4], __shfl(P, 5)*Etr[5]));
      float c2 = fmaf(__shfl(P, 6), Etr[6], fmaf(__shfl(P, 7), Etr[7], __shfl(P, 8)*Etr[8]));
      float c3 = fmaf(__shfl(P, 9), Etr[9], fmaf(__shfl(P,10), Etr[10], __shfl(P,11)*Etr[11]));
      float em = (c0 + c1) + (c2 + c3);
      // slide window
      w0=w1; w1=w2; w2=w3; w3=w4; w4=w5; w5=w6; w6=w7; w7=em;
      // renorm every 4th step (skip after final step)
      if (u == 3 && j < 191) {
        float inv = __builtin_amdgcn_rcpf(p0s);
        w0*=inv; w1*=inv; w2*=inv; w3*=inv; w4*=inv; w5*=inv; w6*=inv; w7*=inv;
        C += __logf(p0s);
      }
      xa0 = xa1; xb0 = xb1; xa1 = xa2; xb1 = xb2;
    }
  }
  float last_na = C + __logf(P);               // na_768[t]
  float contrib = (lane < 11) ? last_na : 0.f; // sum tags 0..10 (:STOP_ID)
  #pragma unroll
  for (int off = 32; off; off >>= 1) contrib += __shfl_down(contrib, off);
  if (lane == 0) out[0] = contrib - gold;
}

// ---------------------------------------------------------------------------
extern "C" void kernel_launch(void* const* d_in, const int* in_sizes, int n_in,
                              void* d_out, int out_size, void* d_ws, size_t ws_size,
                              hipStream_t stream)
{
  const float* feats = (const float*)d_in[0];
  const int*   tags  = (const int*)  d_in[1];
  const float* Wd    = (const float*)d_in[2];
  const float* bd    = (const float*)d_in[3];
  const float* Wl    = (const float*)d_in[4];
  const float* bl    = (const float*)d_in[5];
  const float* Wr    = (const float*)d_in[6];
  const float* br    = (const float*)d_in[7];
  const float* Gl    = (const float*)d_in[8];
  const float* bgl   = (const float*)d_in[9];
  const float* Gr    = (const float*)d_in[10];
  const float* bgr   = (const float*)d_in[11];
  const float* Wt    = (const float*)d_in[12];
  const float* bt    = (const float*)d_in[13];
  const float* trans = (const float*)d_in[14];
  float* out = (float*)d_out;

  char* ws = (char*)d_ws;
  unsigned short* featsB = (unsigned short*)(ws + 0);        // 768*512 bf16
  unsigned short* WdB    = (unsigned short*)(ws + 786432);   // 256*512 bf16
  unsigned short* WcB    = (unsigned short*)(ws + 1048576);  // 1024*512 bf16
  float*          bc     = (float*)         (ws + 2097152);  // 1024 f32
  unsigned short* ht     = (unsigned short*)(ws + 2101248);  // 8*768*256 bf16
  float*          Bband  = (float*)         (ws + 5246976);  // 769*96 f32  (295296 B)
  float*          Bexp   = (float*)         (ws + 5542272);  // 771*96 f32  (296064 B)

  prep_kernel<<<4100, 256, 0, stream>>>(feats, Wd, Wl, Wr, Gl, Gr, bl, br, bgl, bgr,
                                        featsB, WdB, WcB, bc);
  hgemm_kernel<<<dim3(12, 4), 256, 0, stream>>>(featsB, WdB, bd, ht);
  for (int sl = 1; sl <= 7; ++sl)
    iter_kernel<<<dim3(12, 16), 256, 0, stream>>>(ht + (size_t)(sl-1)*768*256, WcB, bc,
                                                  ht + (size_t)sl*768*256, 768 - sl);
  band_kernel<<<768, 128, 0, stream>>>(ht, Wt, bt, Bband, Bexp);
  fwd_kernel<<<1, 64, 0, stream>>>(Bband, Bexp, trans, bt, tags, out);
}

// Round 4
// 258.259 us; speedup vs baseline: 1.6089x; 1.0934x over previous
//
#include <hip/hip_runtime.h>

typedef __attribute__((ext_vector_type(8))) short short8;
typedef __attribute__((ext_vector_type(4))) float f32x4;

#define LC 768
#define DD 256

__device__ __forceinline__ float bf2f(short s) {
  return __uint_as_float(((unsigned)(unsigned short)s) << 16);
}
__device__ __forceinline__ unsigned short f2bf(float f) {
  unsigned u = __float_as_uint(f);
  unsigned rounding = 0x7fffu + ((u >> 16) & 1u);
  return (unsigned short)((u + rounding) >> 16);
}
__device__ __forceinline__ float rdlane(float v, int l) {
  return __int_as_float(__builtin_amdgcn_readlane(__float_as_int(v), l));
}

// ---------------- prep: fp32 -> bf16 conversions + combined weight/bias ----
__global__ void prep_kernel(const float* __restrict__ feats, const float* __restrict__ Wd,
                            const float* __restrict__ Wl, const float* __restrict__ Wr,
                            const float* __restrict__ Gl, const float* __restrict__ Gr,
                            const float* __restrict__ bl, const float* __restrict__ br,
                            const float* __restrict__ bgl, const float* __restrict__ bgr,
                            unsigned short* __restrict__ featsB, unsigned short* __restrict__ WdB,
                            unsigned short* __restrict__ WcB, float* __restrict__ bc)
{
  int idx = blockIdx.x * 256 + threadIdx.x;
  if (idx < 393216) {
    featsB[idx] = f2bf(feats[idx]);
  } else if (idx < 524288) {
    int j = idx - 393216;
    WdB[j] = f2bf(Wd[j]);
  } else if (idx < 1048576) {
    int j = idx - 524288;          // Wc[1024][512]: o = j>>9, k = j&511
    int o = j >> 9, k = j & 511;
    float v;
    if (k < 256) v = (o < 256) ? Wl[o*256 + k] : Gl[(o-256)*256 + k];
    else { int k2 = k - 256; v = (o < 256) ? Wr[o*256 + k2] : Gr[(o-256)*256 + k2]; }
    WcB[j] = f2bf(v);
  } else if (idx < 1049600) {
    int o = idx - 1048576;
    bc[o] = (o < 256) ? bl[o] + br[o] : bgl[o-256] + bgr[o-256];
  }
}

// ---------------- h = feats @ Wd.T + bd  (768x512 @ 512x256) ---------------
__global__ __launch_bounds__(256) void hgemm_kernel(const unsigned short* __restrict__ A,  // [768][512] bf16
                                                    const unsigned short* __restrict__ W,  // [256][512] bf16
                                                    const float* __restrict__ bd,
                                                    unsigned short* __restrict__ C)        // [768][256] bf16
{
  __shared__ __align__(16) unsigned short As[64][72];
  __shared__ __align__(16) unsigned short Ws[64][72];
  int p0 = blockIdx.x * 64;
  int n0 = blockIdx.y * 64;
  int tid = threadIdx.x;
  int wave = tid >> 6, lane = tid & 63;
  f32x4 acc[4];
  #pragma unroll
  for (int i = 0; i < 4; ++i)
    #pragma unroll
    for (int j = 0; j < 4; ++j) acc[i][j] = 0.f;

  int lr = tid >> 3;
  int c8 = (tid & 7) * 8;
  for (int kt = 0; kt < 8; ++kt) {
    int kb = kt * 64;
    #pragma unroll
    for (int rr = 0; rr < 64; rr += 32) {
      int row = lr + rr;
      *(short8*)(&As[row][c8]) = *(const short8*)(A + (size_t)(p0 + row)*512 + kb + c8);
      *(short8*)(&Ws[row][c8]) = *(const short8*)(W + (size_t)(n0 + row)*512 + kb + c8);
    }
    __syncthreads();
    int q8 = (lane >> 4) * 8;
    #pragma unroll
    for (int kk = 0; kk < 2; ++kk) {
      short8 b = *(const short8*)(&Ws[wave*16 + (lane & 15)][kk*32 + q8]);
      #pragma unroll
      for (int mt = 0; mt < 4; ++mt) {
        short8 a = *(const short8*)(&As[mt*16 + (lane & 15)][kk*32 + q8]);
        acc[mt] = __builtin_amdgcn_mfma_f32_16x16x32_bf16(a, b, acc[mt], 0, 0, 0);
      }
    }
    __syncthreads();
  }
  int o = n0 + wave*16 + (lane & 15);
  float bias = bd[o];
  #pragma unroll
  for (int mt = 0; mt < 4; ++mt)
    #pragma unroll
    for (int r = 0; r < 4; ++r) {
      int row = p0 + mt*16 + (lane >> 4)*4 + r;
      C[row*256 + o] = f2bf(acc[mt][r] + bias);
    }
}

// ---------------- one span iteration: GEMM + fused gate epilogue -----------
__global__ __launch_bounds__(256) void iter_kernel(const unsigned short* __restrict__ htp, // [768][256]
                                                   const unsigned short* __restrict__ Wc,  // [1024][512]
                                                   const float* __restrict__ bc,           // [1024]
                                                   unsigned short* __restrict__ htn,       // [768][256]
                                                   int Mvalid)
{
  __shared__ __align__(16) unsigned short As[64][72];
  __shared__ __align__(16) unsigned short Ws[64][72];
  __shared__ float Cs[64][64];
  int p0 = blockIdx.x * 64;
  int n0 = blockIdx.y * 16;
  int tid = threadIdx.x;
  int wave = tid >> 6, lane = tid & 63;
  f32x4 acc[4];
  #pragma unroll
  for (int i = 0; i < 4; ++i)
    #pragma unroll
    for (int j = 0; j < 4; ++j) acc[i][j] = 0.f;

  int lr = tid >> 3;
  int c8 = (tid & 7) * 8;
  for (int kt = 0; kt < 8; ++kt) {
    int kb = kt * 64;
    int shift = kb >> 8;          // 0 for k<256 (l), 1 for k>=256 (r)
    int kcol = kb & 255;
    #pragma unroll
    for (int rr = 0; rr < 64; rr += 32) {
      int row = lr + rr;
      int grow = p0 + row + shift; if (grow > 767) grow = 767;
      *(short8*)(&As[row][c8]) = *(const short8*)(htp + (size_t)grow*256 + kcol + c8);
      int o = (row >> 4)*256 + n0 + (row & 15);
      *(short8*)(&Ws[row][c8]) = *(const short8*)(Wc + (size_t)o*512 + kb + c8);
    }
    __syncthreads();
    int q8 = (lane >> 4) * 8;
    #pragma unroll
    for (int kk = 0; kk < 2; ++kk) {
      short8 b = *(const short8*)(&Ws[wave*16 + (lane & 15)][kk*32 + q8]);
      #pragma unroll
      for (int mt = 0; mt < 4; ++mt) {
        short8 a = *(const short8*)(&As[mt*16 + (lane & 15)][kk*32 + q8]);
        acc[mt] = __builtin_amdgcn_mfma_f32_16x16x32_bf16(a, b, acc[mt], 0, 0, 0);
      }
    }
    __syncthreads();
  }
  #pragma unroll
  for (int mt = 0; mt < 4; ++mt)
    #pragma unroll
    for (int r = 0; r < 4; ++r)
      Cs[mt*16 + (lane >> 4)*4 + r][wave*16 + (lane & 15)] = acc[mt][r];
  __syncthreads();

  int dl = tid & 15;
  int d = n0 + dl;
  float bz = bc[d], b0 = bc[256 + d], b1 = bc[512 + d], b2v = bc[768 + d];
  for (int pr = tid >> 4; pr < 64; pr += 16) {
    int p = p0 + pr;
    if (p >= Mvalid) continue;
    float z  = Cs[pr][dl]      + bz;
    float g0 = Cs[pr][16 + dl] + b0;
    float g1 = Cs[pr][32 + dl] + b1;
    float g2 = Cs[pr][48 + dl] + b2v;
    float l = bf2f((short)htp[p*256 + d]);
    float r = bf2f((short)htp[(p+1)*256 + d]);
    float hh = 4.f / (1.f + __expf(-z)) - 2.f;
    float mg = fmaxf(g0, fmaxf(g1, g2));
    float e0 = __expf(g0 - mg), e1 = __expf(g1 - mg), e2 = __expf(g2 - mg);
    float inv = 1.f / (e0 + e1 + e2);
    htn[p*256 + d] = f2bf((e0*hh + e1*l + e2*r) * inv);
  }
}

// ---------------- band: log scores AND exp(scores) ------------------------
__global__ __launch_bounds__(128) void band_kernel(const unsigned short* __restrict__ htall, // [8][768][256]
                                                   const float* __restrict__ Wt,
                                                   const float* __restrict__ bt,
                                                   float* __restrict__ Bband,                // [769][96]
                                                   float* __restrict__ Bexp)                 // [771][96]
{
  __shared__ __align__(16) unsigned short rows[8][264];
  int i = blockIdx.x + 1;     // 1..768
  int tid = threadIdx.x;
  for (int q = tid; q < 256; q += 128) {
    int k = q >> 5, cc = (q & 31) * 8;
    int p = i - 8 + k, sl = 7 - k;
    short8 v;
    if (p >= 0) {
      v = *(const short8*)(htall + ((size_t)sl*768 + p)*256 + cc);
    } else {
      for (int j = 0; j < 8; ++j) v[j] = 0;
    }
    *(short8*)(&rows[k][cc]) = v;
  }
  __syncthreads();
  if (tid < 96) {
    int t = tid >> 3, k = tid & 7;
    int p = i - 8 + k;
    float res = -1e30f;
    if (p >= 0) {
      float acc = 0.f;
      for (int dch = 0; dch < 256; dch += 8) {
        float4 wa = *(const float4*)(Wt + t*256 + dch);
        float4 wb = *(const float4*)(Wt + t*256 + dch + 4);
        short8 hv = *(const short8*)(&rows[k][dch]);
        acc += wa.x*bf2f(hv[0]) + wa.y*bf2f(hv[1]) + wa.z*bf2f(hv[2]) + wa.w*bf2f(hv[3])
             + wb.x*bf2f(hv[4]) + wb.y*bf2f(hv[5]) + wb.z*bf2f(hv[6]) + wb.w*bf2f(hv[7]);
      }
      res = acc + bt[t];
    }
    Bband[(size_t)i*96 + tid] = res;            // log domain (gold)
    Bexp[(size_t)i*96 + tid]  = __expf(res);    // prob domain (forward); exp(-1e30)=0
  }
}

// ---------------- forward recurrence + gold, single wave, prob domain ------
__global__ __launch_bounds__(64) void fwd_kernel(const float* __restrict__ Bband,
                                                 const float* __restrict__ Bexp,
                                                 const float* __restrict__ trans,
                                                 const float* __restrict__ bt,
                                                 const int* __restrict__ tags,
                                                 float* __restrict__ out)
{
  int lane = threadIdx.x;
  // ---- gold score (log domain) ----
  float gold = 0.f;
  for (int s = lane; s < 96; s += 64) {
    int a = tags[s*4+0], b = tags[s*4+1], c = tags[s*4+2], d = tags[s*4+3];
    float v = trans[c*12 + d];
    int sl = b - a;
    if (sl >= 0 && sl < 8) v += Bband[(size_t)(b+1)*96 + d*8 + (7 - sl)];
    else v += bt[d];
    gold += v;
  }
  #pragma unroll
  for (int off = 32; off; off >>= 1) gold += __shfl_down(gold, off);

  // ---- forward pass in probability domain with running scale C ----
  // lane t owns tag t (lanes >=12 shadow tag 11).
  // window w[k] = exp(m_{i-8+k} - C);  P = exp(na_i - C);
  // w7' = sum_tp P[tp] * exp(trans[tp][t])  via readlane broadcasts (no LDS).
  int tt = lane < 12 ? lane : 11;
  float Etr[12];
  #pragma unroll
  for (int tp = 0; tp < 12; ++tp) Etr[tp] = __expf(trans[tp*12 + tt]);

  float w0=0.f,w1=0.f,w2=0.f,w3=0.f,w4=0.f,w5=0.f,w6=0.f;
  float w7 = Etr[10];          // G(alpha_0): only START has mass exp(0)=1
  float C = 0.f;

  const float* bp = Bexp + (size_t)tt*8;
  float4 xa0 = *(const float4*)(bp + 96);
  float4 xb0 = *(const float4*)(bp + 96 + 4);
  float4 xa1 = *(const float4*)(bp + 192);
  float4 xb1 = *(const float4*)(bp + 192 + 4);
  float P = 1.f;

  for (int j = 0; j < 192; ++j) {
    #pragma unroll
    for (int u = 0; u < 4; ++u) {
      int i = j*4 + u + 1;
      // prefetch row i+2 (distance-2: ~2 iterations covers L2 latency)
      float4 xa2 = *(const float4*)(bp + (size_t)(i+2)*96);
      float4 xb2 = *(const float4*)(bp + (size_t)(i+2)*96 + 4);
      // P = sum_k eX[k]*w[k]; terms with w0..w5 are off the critical path
      float t01 = fmaf(xa0.x, w0, xa0.y*w1);
      float t23 = fmaf(xa0.z, w2, xa0.w*w3);
      float t45 = fmaf(xb0.x, w4, xb0.y*w5);
      float partial = (t01 + t23) + t45;
      P = fmaf(xb0.w, w7, fmaf(xb0.z, w6, partial));
      // broadcast P[tp] via readlane (VALU-rate, no LDS latency)
      float s0  = rdlane(P, 0),  s1  = rdlane(P, 1),  s2  = rdlane(P, 2);
      float s3  = rdlane(P, 3),  s4  = rdlane(P, 4),  s5  = rdlane(P, 5);
      float s6  = rdlane(P, 6),  s7  = rdlane(P, 7),  s8  = rdlane(P, 8);
      float s9  = rdlane(P, 9),  s10 = rdlane(P,10),  s11 = rdlane(P,11);
      float c0 = fmaf(s0, Etr[0], fmaf(s1,  Etr[1],  s2*Etr[2]));
      float c1 = fmaf(s3, Etr[3], fmaf(s4,  Etr[4],  s5*Etr[5]));
      float c2 = fmaf(s6, Etr[6], fmaf(s7,  Etr[7],  s8*Etr[8]));
      float c3 = fmaf(s9, Etr[9], fmaf(s10, Etr[10], s11*Etr[11]));
      float em = (c0 + c1) + (c2 + c3);
      // slide window
      w0=w1; w1=w2; w2=w3; w3=w4; w4=w5; w5=w6; w6=w7; w7=em;
      // renorm every 4th step (skip after final step); scale = s0 = P[tag0]
      if (u == 3 && j < 191) {
        float inv = __builtin_amdgcn_rcpf(s0);
        w0*=inv; w1*=inv; w2*=inv; w3*=inv; w4*=inv; w5*=inv; w6*=inv; w7*=inv;
        C += __logf(s0);
      }
      xa0 = xa1; xb0 = xb1; xa1 = xa2; xb1 = xb2;
    }
  }
  float last_na = C + __logf(P);               // na_768[t]
  float contrib = (lane < 11) ? last_na : 0.f; // sum tags 0..10 (:STOP_ID)
  #pragma unroll
  for (int off = 32; off; off >>= 1) contrib += __shfl_down(contrib, off);
  if (lane == 0) out[0] = contrib - gold;
}

// ---------------------------------------------------------------------------
extern "C" void kernel_launch(void* const* d_in, const int* in_sizes, int n_in,
                              void* d_out, int out_size, void* d_ws, size_t ws_size,
                              hipStream_t stream)
{
  const float* feats = (const float*)d_in[0];
  const int*   tags  = (const int*)  d_in[1];
  const float* Wd    = (const float*)d_in[2];
  const float* bd    = (const float*)d_in[3];
  const float* Wl    = (const float*)d_in[4];
  const float* bl    = (const float*)d_in[5];
  const float* Wr    = (const float*)d_in[6];
  const float* br    = (const float*)d_in[7];
  const float* Gl    = (const float*)d_in[8];
  const float* bgl   = (const float*)d_in[9];
  const float* Gr    = (const float*)d_in[10];
  const float* bgr   = (const float*)d_in[11];
  const float* Wt    = (const float*)d_in[12];
  const float* bt    = (const float*)d_in[13];
  const float* trans = (const float*)d_in[14];
  float* out = (float*)d_out;

  char* ws = (char*)d_ws;
  unsigned short* featsB = (unsigned short*)(ws + 0);        // 768*512 bf16
  unsigned short* WdB    = (unsigned short*)(ws + 786432);   // 256*512 bf16
  unsigned short* WcB    = (unsigned short*)(ws + 1048576);  // 1024*512 bf16
  float*          bc     = (float*)         (ws + 2097152);  // 1024 f32
  unsigned short* ht     = (unsigned short*)(ws + 2101248);  // 8*768*256 bf16
  float*          Bband  = (float*)         (ws + 5246976);  // 769*96 f32  (295296 B)
  float*          Bexp   = (float*)         (ws + 5542272);  // 771*96 f32  (296064 B)

  prep_kernel<<<4100, 256, 0, stream>>>(feats, Wd, Wl, Wr, Gl, Gr, bl, br, bgl, bgr,
                                        featsB, WdB, WcB, bc);
  hgemm_kernel<<<dim3(12, 4), 256, 0, stream>>>(featsB, WdB, bd, ht);
  for (int sl = 1; sl <= 7; ++sl)
    iter_kernel<<<dim3(12, 16), 256, 0, stream>>>(ht + (size_t)(sl-1)*768*256, WcB, bc,
                                                  ht + (size_t)sl*768*256, 768 - sl);
  band_kernel<<<768, 128, 0, stream>>>(ht, Wt, bt, Bband, Bexp);
  fwd_kernel<<<1, 64, 0, stream>>>(Bband, Bexp, trans, bt, tags, out);
}